// Round 7
// baseline (382.837 us; speedup 1.0000x reference)
//
#include <hip/hip_runtime.h>

#define TT 65536
#define R2 16384

typedef _Float16 f16x8 __attribute__((ext_vector_type(8)));
typedef float    f32x4 __attribute__((ext_vector_type(4)));
typedef unsigned u32x4 __attribute__((ext_vector_type(4)));

#define MFMA16 __builtin_amdgcn_mfma_f32_16x16x32_f16

// lt row stride: 136 halfs = 272 B = 17*16 B  (bank-decorrelated, 16B-aligned)
#define LTS 136
// per-wave lt tile: 16 rows * 136 halfs
#define LTW 2176

// ---- helpers ----
__device__ __forceinline__ unsigned short f2h(float f){
    _Float16 h = (_Float16)f;
    return __builtin_bit_cast(unsigned short, h);
}
__device__ __forceinline__ float h2f(unsigned short u){
    return (float)__builtin_bit_cast(_Float16, u);
}
__device__ __forceinline__ unsigned relu2(unsigned w){
    unsigned s = w & 0x80008000u;
    unsigned mask = ((s >> 15) * 0x7FFFu) | s;
    return w & ~mask;
}
__device__ __forceinline__ float nrm(float a){
    float v = a / 1.101f + 0.5f;
    v = fmaxf(v, 0.0f);
    v = fminf(v, 0.99999f);
    return v;
}
#define VMCNT0() asm volatile("s_waitcnt vmcnt(0)" ::: "memory")
#define LGKM0()  asm volatile("s_waitcnt lgkmcnt(0)" ::: "memory")

// ---- repack weights f32 -> f16 B-fragment layout (LDS-tiled, coalesced);
//      also zeroes the histogram buffer (cp) ----
__global__ __launch_bounds__(256) void k_repack(const float* __restrict__ W0,
        const float* __restrict__ W1, const float* __restrict__ Ws,
        const float* __restrict__ Wc, unsigned short* __restrict__ out,
        int* __restrict__ cnt){
    __shared__ unsigned short lh[4096];
    int b = blockIdx.x, tid = threadIdx.x;

    int gid = b*256 + tid;
    if (gid < 24576){ u32x4 z = {0,0,0,0}; ((u32x4*)cnt)[gid] = z; }

    const float* src; int obase;
    if (b < 100){
        int i = b/20, rr = b%20;
        if (rr < 8){       src = W0 + (size_t)i*32768 + rr*4096;      obase = i*81920 + rr*4096; }
        else if (rr < 12){ int ks=rr-8;  src = W1 + (size_t)i*16384 + ks*4096; obase = i*81920 + 32768 + ks*4096; }
        else {             int ks=rr-12; src = Ws + (size_t)i*32768 + ks*4096; obase = i*81920 + 49152 + ks*4096; }
    } else { int ks = b-100; src = Wc + ks*4096; obase = 409600 + ks*4096; }

    #pragma unroll
    for (int m = 0; m < 16; m++){
        int gi = m*256 + tid;
        lh[gi] = f2h(src[gi]);
    }
    __syncthreads();

    #pragma unroll
    for (int g2 = 0; g2 < 2; g2++){
        int base = tid*16 + g2*8;
        int l = (base >> 3) & 63, t = (base >> 9) & 7;
        int n = t*16 + (l & 15), kb = (l >> 4)*8;
        unsigned short h[8];
        #pragma unroll
        for (int j = 0; j < 8; j++) h[j] = lh[(kb + j)*128 + n];
        u32x4 pk;
        #pragma unroll
        for (int q = 0; q < 4; q++)
            pk[q] = (unsigned)h[2*q] | ((unsigned)h[2*q+1] << 16);
        *(u32x4*)(&out[obase + base]) = pk;
    }
}

// ---- indices + histogram (fused) ----
__global__ __launch_bounds__(256) void k_idxhist(const float* __restrict__ p,
        int* __restrict__ idx, int* __restrict__ cnt){
    int pt = blockIdx.x*256 + threadIdx.x;
    float p0 = p[pt*3+0], p1 = p[pt*3+1], p2 = p[pt*3+2];
    int g0 = (int)(nrm(p0)*128.f);
    int g1 = (int)(nrm(p1)*128.f);
    int g2 = (int)(nrm(p2)*128.f);
    int i0 = g0 + 128*g2, i1 = g0 + 128*g1, i2 = g1 + 128*g2;
    idx[0*TT + pt] = i0;
    idx[1*TT + pt] = i1;
    idx[2*TT + pt] = i2;
    int b14 = (pt >> 15) << 14;
    atomicAdd(&cnt[0*32768 + b14 + i0], 1);
    atomicAdd(&cnt[1*32768 + b14 + i1], 1);
    atomicAdd(&cnt[2*32768 + b14 + i2], 1);
}

// ---- exclusive scan (1 block of 1024 per plane); cnt may alias cp ----
__global__ __launch_bounds__(1024) void k_scan(const int* cnt,
        int* __restrict__ cs, int* cp){
    __shared__ int wsum[16];
    int pl = blockIdx.x, tid = threadIdx.x;
    int lane = tid & 63, wid = tid >> 6;
    const int* c = cnt + pl*32768;
    int v[32], tot = 0;
    #pragma unroll
    for (int j = 0; j < 32; j++){ v[j] = c[tid*32 + j]; tot += v[j]; }
    int x = tot;
    #pragma unroll
    for (int off = 1; off < 64; off <<= 1){
        int y = __shfl_up(x, off, 64);
        if (lane >= off) x += y;
    }
    if (lane == 63) wsum[wid] = x;
    __syncthreads();
    int woff = 0;
    #pragma unroll
    for (int j = 0; j < 16; j++) woff += (j < wid) ? wsum[j] : 0;
    int run = woff + x - tot;
    #pragma unroll
    for (int j = 0; j < 32; j++){
        cs[pl*32769 + tid*32 + j] = run;
        cp[pl*32768 + tid*32 + j] = run;
        run += v[j];
    }
    if (tid == 1023) cs[pl*32769 + 32768] = TT;
}

// ---- counting sort: scatter point ids ----
__global__ __launch_bounds__(256) void k_scatter(const int* __restrict__ idx,
        int* __restrict__ cp, int* __restrict__ srt){
    int pt = blockIdx.x*256 + threadIdx.x;
    int b14 = (pt >> 15) << 14;
    #pragma unroll
    for (int pl = 0; pl < 3; pl++){
        int pos = atomicAdd(&cp[pl*32768 + b14 + idx[pl*TT + pt]], 1);
        srt[pl*TT + pos] = pt;
    }
}

// ---- per-cell max -> mxp[pl][b*R2+cell][128] (f16), packed-f16 max ----
__global__ __launch_bounds__(256) void k_pool3(const unsigned short* __restrict__ xb,
        const int* __restrict__ srt, const int* __restrict__ cs,
        unsigned short* __restrict__ mxp){
    int pl = blockIdx.y;
    const int* srtp = srt + (size_t)pl*TT;
    const int* csp  = cs  + (size_t)pl*32769;
    int lane = threadIdx.x & 63, w = threadIdx.x >> 6;
    int g = lane >> 4, l16 = lane & 15;
    int cbase = (blockIdx.x*4 + w)*4;
    for (int c = cbase; c < cbase + 4; c++){
        int s = csp[c], e = csp[c+1];
        if (s == e) continue;
        f16x8 m;
        #pragma unroll
        for (int j = 0; j < 8; j++) m[j] = (_Float16)(-65504.f);
        for (int i = s + g; i < e; i += 4){
            int pt = srtp[i];
            f16x8 v = *(const f16x8*)(xb + (size_t)pt*128 + l16*8);
            #pragma unroll
            for (int j = 0; j < 8; j++)
                m[j] = (v[j] > m[j]) ? v[j] : m[j];
        }
        #pragma unroll
        for (int sh = 16; sh <= 32; sh += 16){
            u32x4 um = __builtin_bit_cast(u32x4, m);
            u32x4 o;
            #pragma unroll
            for (int q = 0; q < 4; q++) o[q] = __shfl_xor(um[q], sh, 64);
            f16x8 vm = __builtin_bit_cast(f16x8, o);
            #pragma unroll
            for (int j = 0; j < 8; j++)
                m[j] = (vm[j] > m[j]) ? vm[j] : m[j];
        }
        if (g == 0)
            ((u32x4*)(mxp + ((size_t)pl*32768 + c)*128))[l16] =
                __builtin_bit_cast(u32x4, m);
    }
}

// ============================================================
// fused ResnetBlockFC, M=16/wave, full-tile lt transform
// (releases acc before acc2 -> peak regs < 128), 49 KB LDS,
// global_load_lds weight staging. MODE: 0=head, 1=mid, 2=tail
// ============================================================
template<int MODE>
__device__ __forceinline__ void resnet_body(
        const unsigned short* __restrict__ xin,
        unsigned short* __restrict__ xout,
        const unsigned short* __restrict__ wp,
        const float* __restrict__ b0, const float* __restrict__ b1,
        const int* __restrict__ idx, const unsigned short* __restrict__ mxp,
        const float* __restrict__ pin, const float* __restrict__ fW,
        const float* __restrict__ fb,
        const unsigned short* __restrict__ wc, const float* __restrict__ bc,
        unsigned short* lw, unsigned short* lt){
    int tid = threadIdx.x, w = tid >> 6, lane = tid & 63;
    int quad = lane >> 4, l15 = lane & 15;
    int m0 = blockIdx.x*64 + w*16;
    unsigned short* ltw = lt + w*LTW;

    auto stage = [&](const unsigned short* src){
        #pragma unroll
        for (int i = 0; i < 8; i++){
            int chunk = i*4 + w;
            __builtin_amdgcn_global_load_lds(
                (const __attribute__((address_space(1))) unsigned*)(src + chunk*512 + lane*8),
                (__attribute__((address_space(3))) unsigned*)(lw + chunk*512),
                16, 0, 0);
        }
    };
    auto gemm = [&](const f16x8* a, f32x4 (&ac)[8]){
        #pragma unroll
        for (int ks = 0; ks < 4; ks++){
            #pragma unroll
            for (int t = 0; t < 8; t++){
                f16x8 b = *(const f16x8*)&lw[((ks*8 + t)*64 + lane)*8];
                ac[t] = MFMA16(a[ks], b, ac[t], 0, 0, 0);
            }
        }
    };

    stage(wp);   // W0a in flight during A-fragment setup

    // ---- A fragments ----
    u32x4 xf[4]; f16x8 pf[4];
    if (MODE == 0){
        int row = m0 + l15;
        float p0 = pin[row*3+0], p1 = pin[row*3+1], p2 = pin[row*3+2];
        #pragma unroll
        for (int ks = 0; ks < 4; ks++){
            int c0 = ks*32 + quad*8;
            unsigned short hx[8], hp[8];
            #pragma unroll
            for (int h = 0; h < 2; h++){
                f32x4 w0 = *(const f32x4*)(fW + c0 + h*4);
                f32x4 w1 = *(const f32x4*)(fW + 256 + c0 + h*4);
                f32x4 w2 = *(const f32x4*)(fW + 512 + c0 + h*4);
                f32x4 bb = *(const f32x4*)(fb + c0 + h*4);
                f32x4 v0 = *(const f32x4*)(fW + 128 + c0 + h*4);
                f32x4 v1 = *(const f32x4*)(fW + 384 + c0 + h*4);
                f32x4 v2 = *(const f32x4*)(fW + 640 + c0 + h*4);
                f32x4 bp = *(const f32x4*)(fb + 128 + c0 + h*4);
                #pragma unroll
                for (int j = 0; j < 4; j++){
                    hx[h*4+j] = f2h(bb[j] + p0*w0[j] + p1*w1[j] + p2*w2[j]);
                    hp[h*4+j] = f2h(bp[j] + p0*v0[j] + p1*v1[j] + p2*v2[j]);
                }
            }
            unsigned short* dx = (unsigned short*)&xf[ks];
            unsigned short* dp = (unsigned short*)&pf[ks];
            #pragma unroll
            for (int j = 0; j < 8; j++){ dx[j] = hx[j]; dp[j] = hp[j]; }
        }
    } else {
        int row = m0 + l15;
        size_t rb = (size_t)row*128;
        #pragma unroll
        for (int ks = 0; ks < 4; ks++)
            xf[ks] = *(const u32x4*)(xin + rb + ks*32 + quad*8);
        int b14 = (row >> 15) << 14;
        const unsigned short* q0 = mxp + ((size_t)(0*32768 + b14 + idx[row]))*128;
        const unsigned short* q1 = mxp + ((size_t)(1*32768 + b14 + idx[TT + row]))*128;
        const unsigned short* q2 = mxp + ((size_t)(2*32768 + b14 + idx[2*TT + row]))*128;
        #pragma unroll
        for (int ks = 0; ks < 4; ks++){
            int col = ks*32 + quad*8;
            f16x8 a = *(const f16x8*)(q0 + col);
            f16x8 b = *(const f16x8*)(q1 + col);
            f16x8 c = *(const f16x8*)(q2 + col);
            pf[ks] = a + b + c;                 // packed f16 adds
        }
    }

    f32x4 acc[8];
    #pragma unroll
    for (int t = 0; t < 8; t++){ f32x4 z = {0.f,0.f,0.f,0.f}; acc[t] = z; }

    VMCNT0(); __syncthreads();                  // W0a staged

    // ---- phase 0: relu(xf) @ W0a ----
    {
        f16x8 a[4];
        #pragma unroll
        for (int ks = 0; ks < 4; ks++){
            u32x4 u = xf[ks];
            u.x = relu2(u.x); u.y = relu2(u.y); u.z = relu2(u.z); u.w = relu2(u.w);
            a[ks] = __builtin_bit_cast(f16x8, u);
        }
        gemm(a, acc);
    }
    __syncthreads();
    stage(wp + 16384);
    VMCNT0(); __syncthreads();                  // W0b staged

    // ---- phase 1: relu(pf) @ W0b ----
    {
        f16x8 a[4];
        #pragma unroll
        for (int ks = 0; ks < 4; ks++){
            u32x4 u = __builtin_bit_cast(u32x4, pf[ks]);
            u.x = relu2(u.x); u.y = relu2(u.y); u.z = relu2(u.z); u.w = relu2(u.w);
            a[ks] = __builtin_bit_cast(f16x8, u);
        }
        gemm(a, acc);
    }
    __syncthreads();
    stage(wp + 32768);
    VMCNT0(); __syncthreads();                  // W1 staged

    // ---- phase 2: full-tile relu(net+b0) -> lt (releases acc), GEMM2 @ W1 ----
    {
        float b0v[8];
        #pragma unroll
        for (int t = 0; t < 8; t++) b0v[t] = b0[t*16 + l15];
        #pragma unroll
        for (int t = 0; t < 8; t++)
            #pragma unroll
            for (int r = 0; r < 4; r++){
                float v = fmaxf(acc[t][r] + b0v[t], 0.f);
                ltw[(quad*4 + r)*LTS + t*16 + l15] = f2h(v);
            }
    }
    LGKM0();
    f32x4 acc2[8];
    {
        #pragma unroll
        for (int t = 0; t < 8; t++){
            float bv = b1[t*16 + l15];
            f32x4 iv = {bv, bv, bv, bv};
            acc2[t] = iv;
        }
    }
    #pragma unroll
    for (int ks = 0; ks < 4; ks++){
        f16x8 a0 = *(const f16x8*)&ltw[l15*LTS + ks*32 + quad*8];
        #pragma unroll
        for (int t = 0; t < 8; t++){
            f16x8 b = *(const f16x8*)&lw[((ks*8 + t)*64 + lane)*8];
            acc2[t] = MFMA16(a0, b, acc2[t], 0, 0, 0);
        }
    }
    __syncthreads();
    stage(wp + 49152);
    VMCNT0(); __syncthreads();                  // Wsa staged

    // ---- phase 3: xf @ Wsa ----
    {
        f16x8 a[4];
        #pragma unroll
        for (int ks = 0; ks < 4; ks++)
            a[ks] = __builtin_bit_cast(f16x8, xf[ks]);
        gemm(a, acc2);
    }
    __syncthreads();
    stage(wp + 65536);
    VMCNT0(); __syncthreads();                  // Wsb staged

    // ---- phase 4: pf @ Wsb ----
    gemm(pf, acc2);

    if (MODE != 2){
        #pragma unroll
        for (int t = 0; t < 8; t++)
            #pragma unroll
            for (int r = 0; r < 4; r++){
                int row = m0 + quad*4 + r;
                xout[(size_t)row*128 + t*16 + l15] = f2h(acc2[t][r]);
            }
        return;
    }
    __syncthreads();
    stage(wc);
    VMCNT0(); __syncthreads();                  // Wc staged

    // ---- phase 5: full-tile net -> lt (no relu), GEMMc @ Wc ----
    #pragma unroll
    for (int t = 0; t < 8; t++)
        #pragma unroll
        for (int r = 0; r < 4; r++)
            ltw[(quad*4 + r)*LTS + t*16 + l15] = f2h(acc2[t][r]);
    LGKM0();
    f32x4 acc3[8];
    #pragma unroll
    for (int t = 0; t < 8; t++){
        float bv = bc[t*16 + l15];
        f32x4 iv = {bv, bv, bv, bv};
        acc3[t] = iv;
    }
    #pragma unroll
    for (int ks = 0; ks < 4; ks++){
        f16x8 a0 = *(const f16x8*)&ltw[l15*LTS + ks*32 + quad*8];
        #pragma unroll
        for (int t = 0; t < 8; t++){
            f16x8 b = *(const f16x8*)&lw[((ks*8 + t)*64 + lane)*8];
            acc3[t] = MFMA16(a0, b, acc3[t], 0, 0, 0);
        }
    }
    #pragma unroll
    for (int t = 0; t < 8; t++)
        #pragma unroll
        for (int r = 0; r < 4; r++){
            int row = m0 + quad*4 + r;
            xout[(size_t)row*128 + t*16 + l15] = f2h(acc3[t][r]);
        }
}

__global__ __launch_bounds__(256, 2) void k_resnet_head(
        unsigned short* __restrict__ xout, const unsigned short* __restrict__ wp,
        const float* __restrict__ b0, const float* __restrict__ b1,
        const float* __restrict__ pin, const float* __restrict__ fW,
        const float* __restrict__ fb){
    __shared__ __align__(16) unsigned short lw[16384];
    __shared__ __align__(16) unsigned short lt[8704];
    resnet_body<0>(nullptr, xout, wp, b0, b1, nullptr, nullptr,
                   pin, fW, fb, nullptr, nullptr, lw, lt);
}
__global__ __launch_bounds__(256, 3) void k_resnet_mid(
        const unsigned short* __restrict__ xin, unsigned short* __restrict__ xout,
        const unsigned short* __restrict__ wp,
        const float* __restrict__ b0, const float* __restrict__ b1,
        const int* __restrict__ idx, const unsigned short* __restrict__ mxp){
    __shared__ __align__(16) unsigned short lw[16384];
    __shared__ __align__(16) unsigned short lt[8704];
    resnet_body<1>(xin, xout, wp, b0, b1, idx, mxp,
                   nullptr, nullptr, nullptr, nullptr, nullptr, lw, lt);
}
__global__ __launch_bounds__(256, 3) void k_resnet_tail(
        const unsigned short* __restrict__ xin, unsigned short* __restrict__ xout,
        const unsigned short* __restrict__ wp,
        const float* __restrict__ b0, const float* __restrict__ b1,
        const int* __restrict__ idx, const unsigned short* __restrict__ mxp,
        const unsigned short* __restrict__ wc, const float* __restrict__ bc){
    __shared__ __align__(16) unsigned short lw[16384];
    __shared__ __align__(16) unsigned short lt[8704];
    resnet_body<2>(xin, xout, wp, b0, b1, idx, mxp,
                   nullptr, nullptr, nullptr, wc, bc, lw, lt);
}

// ---- scatter-mean + transpose, all planes in one launch ----
__global__ __launch_bounds__(256) void k_psum3(const unsigned short* __restrict__ cb,
        const int* __restrict__ srt, const int* __restrict__ cs,
        float* __restrict__ out){
    __shared__ float ls[32*129];
    int pl = blockIdx.y;
    const int* srtp = srt + (size_t)pl*TT;
    const int* csp  = cs  + (size_t)pl*32769;
    int tid = threadIdx.x;
    int lane = tid & 63, w = tid >> 6;
    int g = lane >> 4, l16 = lane & 15;
    int c0 = blockIdx.x * 32;
    for (int cc = w*8; cc < w*8 + 8; cc++){
        int c = c0 + cc;
        int s = csp[c], e = csp[c+1];
        float fs[8];
        #pragma unroll
        for (int j = 0; j < 8; j++) fs[j] = 0.f;
        for (int i = s + g; i < e; i += 4){
            int pt = srtp[i];
            u32x4 v = *(const u32x4*)(cb + (size_t)pt*128 + l16*8);
            #pragma unroll
            for (int q = 0; q < 4; q++){
                unsigned u = v[q];
                fs[2*q]   += h2f((unsigned short)(u & 0xFFFF));
                fs[2*q+1] += h2f((unsigned short)(u >> 16));
            }
        }
        #pragma unroll
        for (int j = 0; j < 8; j++){
            fs[j] += __shfl_xor(fs[j], 16, 64);
            fs[j] += __shfl_xor(fs[j], 32, 64);
        }
        float rc = (e > s) ? 1.f/(float)(e - s) : 0.f;
        if (g == 0){
            #pragma unroll
            for (int j = 0; j < 8; j++) ls[cc*129 + l16*8 + j] = fs[j]*rc;
        }
    }
    __syncthreads();
    int pb = pl*2 + (c0 >> 14);
    float* o = out + (size_t)pb*128*R2 + (c0 & 16383);
    #pragma unroll
    for (int k = 0; k < 16; k++){
        int lin = k*256 + tid;
        int f = lin >> 5, cc = lin & 31;
        o[(size_t)f*R2 + cc] = ls[cc*129 + f];
    }
}

extern "C" void kernel_launch(void* const* d_in, const int* in_sizes, int n_in,
                              void* d_out, int out_size, void* d_ws, size_t ws_size,
                              hipStream_t stream) {
    const float* p        = (const float*)d_in[0];
    const float* fc_pos_W = (const float*)d_in[1];
    const float* fc_pos_b = (const float*)d_in[2];
    const float* bW0      = (const float*)d_in[3];
    const float* bb0      = (const float*)d_in[4];
    const float* bW1      = (const float*)d_in[5];
    const float* bb1      = (const float*)d_in[6];
    const float* bWs      = (const float*)d_in[7];
    const float* fc_c_W   = (const float*)d_in[8];
    const float* fc_c_b   = (const float*)d_in[9];
    float* out = (float*)d_out;

    char* ws = (char*)d_ws;
    int*            idx   = (int*)ws;                          //    786,432 B
    unsigned short* net0  = (unsigned short*)(ws + 786432);    // 16,777,216 B
    unsigned short* net1  = (unsigned short*)(ws + 17563648);  // 16,777,216 B
    unsigned short* cbuf  = (unsigned short*)(ws + 34340864);  // 16,777,216 B
    int*            srt   = (int*)(ws + 51118080);             //    786,432 B
    int*            cs    = (int*)(ws + 51904512);             //    393,232 B
    int*            cp    = (int*)(ws + 52297744);             //    393,216 B
    unsigned short* wpack = (unsigned short*)(ws + 52690960);  //    851,968 B
    unsigned short* mxp   = (unsigned short*)(ws + 53542928);  // 25,165,824 B

    k_repack <<<104, 256, 0, stream>>>(bW0, bW1, bWs, fc_c_W, wpack, cp);
    k_idxhist<<<256, 256, 0, stream>>>(p, idx, cp);
    k_scan   <<<3, 1024, 0, stream>>>(cp, cs, cp);
    k_scatter<<<256, 256, 0, stream>>>(idx, cp, srt);

    // resnet 0: fc_pos fused -> net0
    k_resnet_head<<<1024, 256, 0, stream>>>(net0, wpack, bb0, bb1,
            p, fc_pos_W, fc_pos_b);

    // resnet 1..3: pool -> mxp, gather-resnet, ping-pong
    k_pool3<<<dim3(2048, 3), 256, 0, stream>>>(net0, srt, cs, mxp);
    k_resnet_mid<<<1024, 256, 0, stream>>>(net0, net1, wpack + 81920,
            bb0 + 128, bb1 + 128, idx, mxp);
    k_pool3<<<dim3(2048, 3), 256, 0, stream>>>(net1, srt, cs, mxp);
    k_resnet_mid<<<1024, 256, 0, stream>>>(net1, net0, wpack + 163840,
            bb0 + 256, bb1 + 256, idx, mxp);
    k_pool3<<<dim3(2048, 3), 256, 0, stream>>>(net0, srt, cs, mxp);
    k_resnet_mid<<<1024, 256, 0, stream>>>(net0, net1, wpack + 245760,
            bb0 + 384, bb1 + 384, idx, mxp);
    // resnet 4: fused fc_c -> cbuf
    k_pool3<<<dim3(2048, 3), 256, 0, stream>>>(net1, srt, cs, mxp);
    k_resnet_tail<<<1024, 256, 0, stream>>>(net1, cbuf, wpack + 327680,
            bb0 + 512, bb1 + 512, idx, mxp, wpack + 409600, fc_c_b);

    k_psum3<<<dim3(1024, 3), 256, 0, stream>>>(cbuf, srt, cs, out);
}

// Round 8
// 361.486 us; speedup vs baseline: 1.0591x; 1.0591x over previous
//
#include <hip/hip_runtime.h>

#define TT 65536
#define R2 16384

typedef _Float16 f16x8 __attribute__((ext_vector_type(8)));
typedef float    f32x4 __attribute__((ext_vector_type(4)));
typedef unsigned u32x4 __attribute__((ext_vector_type(4)));

#define MFMA16 __builtin_amdgcn_mfma_f32_16x16x32_f16

// lt row stride: 136 halfs = 272 B (bank-decorrelated, 16B-aligned)
#define LTS 136
// per-wave lt tile: 16 rows * 136 halfs
#define LTW 2176

// ---- helpers ----
__device__ __forceinline__ unsigned short f2h(float f){
    _Float16 h = (_Float16)f;
    return __builtin_bit_cast(unsigned short, h);
}
__device__ __forceinline__ float h2f(unsigned short u){
    return (float)__builtin_bit_cast(_Float16, u);
}
__device__ __forceinline__ unsigned relu2(unsigned w){
    unsigned s = w & 0x80008000u;
    unsigned mask = ((s >> 15) * 0x7FFFu) | s;
    return w & ~mask;
}
__device__ __forceinline__ float nrm(float a){
    float v = a / 1.101f + 0.5f;
    v = fmaxf(v, 0.0f);
    v = fminf(v, 0.99999f);
    return v;
}
#define VMCNT0() asm volatile("s_waitcnt vmcnt(0)" ::: "memory")
#define LGKM0()  asm volatile("s_waitcnt lgkmcnt(0)" ::: "memory")
#define SB0()    __builtin_amdgcn_sched_barrier(0)

// ---- repack weights f32 -> f16 B-fragment layout; zeroes histogram ----
__global__ __launch_bounds__(256) void k_repack(const float* __restrict__ W0,
        const float* __restrict__ W1, const float* __restrict__ Ws,
        const float* __restrict__ Wc, unsigned short* __restrict__ out,
        int* __restrict__ cnt){
    __shared__ unsigned short lh[4096];
    int b = blockIdx.x, tid = threadIdx.x;

    int gid = b*256 + tid;
    if (gid < 24576){ u32x4 z = {0,0,0,0}; ((u32x4*)cnt)[gid] = z; }

    const float* src; int obase;
    if (b < 100){
        int i = b/20, rr = b%20;
        if (rr < 8){       src = W0 + (size_t)i*32768 + rr*4096;      obase = i*81920 + rr*4096; }
        else if (rr < 12){ int ks=rr-8;  src = W1 + (size_t)i*16384 + ks*4096; obase = i*81920 + 32768 + ks*4096; }
        else {             int ks=rr-12; src = Ws + (size_t)i*32768 + ks*4096; obase = i*81920 + 49152 + ks*4096; }
    } else { int ks = b-100; src = Wc + ks*4096; obase = 409600 + ks*4096; }

    #pragma unroll
    for (int m = 0; m < 16; m++){
        int gi = m*256 + tid;
        lh[gi] = f2h(src[gi]);
    }
    __syncthreads();

    #pragma unroll
    for (int g2 = 0; g2 < 2; g2++){
        int base = tid*16 + g2*8;
        int l = (base >> 3) & 63, t = (base >> 9) & 7;
        int n = t*16 + (l & 15), kb = (l >> 4)*8;
        unsigned short h[8];
        #pragma unroll
        for (int j = 0; j < 8; j++) h[j] = lh[(kb + j)*128 + n];
        u32x4 pk;
        #pragma unroll
        for (int q = 0; q < 4; q++)
            pk[q] = (unsigned)h[2*q] | ((unsigned)h[2*q+1] << 16);
        *(u32x4*)(&out[obase + base]) = pk;
    }
}

// ---- indices + histogram (fused) ----
__global__ __launch_bounds__(256) void k_idxhist(const float* __restrict__ p,
        int* __restrict__ idx, int* __restrict__ cnt){
    int pt = blockIdx.x*256 + threadIdx.x;
    float p0 = p[pt*3+0], p1 = p[pt*3+1], p2 = p[pt*3+2];
    int g0 = (int)(nrm(p0)*128.f);
    int g1 = (int)(nrm(p1)*128.f);
    int g2 = (int)(nrm(p2)*128.f);
    int i0 = g0 + 128*g2, i1 = g0 + 128*g1, i2 = g1 + 128*g2;
    idx[0*TT + pt] = i0;
    idx[1*TT + pt] = i1;
    idx[2*TT + pt] = i2;
    int b14 = (pt >> 15) << 14;
    atomicAdd(&cnt[0*32768 + b14 + i0], 1);
    atomicAdd(&cnt[1*32768 + b14 + i1], 1);
    atomicAdd(&cnt[2*32768 + b14 + i2], 1);
}

// ---- exclusive scan (1 block of 1024 per plane); cnt may alias cp ----
__global__ __launch_bounds__(1024) void k_scan(const int* cnt,
        int* __restrict__ cs, int* cp){
    __shared__ int wsum[16];
    int pl = blockIdx.x, tid = threadIdx.x;
    int lane = tid & 63, wid = tid >> 6;
    const int* c = cnt + pl*32768;
    int v[32], tot = 0;
    #pragma unroll
    for (int j = 0; j < 32; j++){ v[j] = c[tid*32 + j]; tot += v[j]; }
    int x = tot;
    #pragma unroll
    for (int off = 1; off < 64; off <<= 1){
        int y = __shfl_up(x, off, 64);
        if (lane >= off) x += y;
    }
    if (lane == 63) wsum[wid] = x;
    __syncthreads();
    int woff = 0;
    #pragma unroll
    for (int j = 0; j < 16; j++) woff += (j < wid) ? wsum[j] : 0;
    int run = woff + x - tot;
    #pragma unroll
    for (int j = 0; j < 32; j++){
        cs[pl*32769 + tid*32 + j] = run;
        cp[pl*32768 + tid*32 + j] = run;
        run += v[j];
    }
    if (tid == 1023) cs[pl*32769 + 32768] = TT;
}

// ---- counting sort: scatter point ids ----
__global__ __launch_bounds__(256) void k_scatter(const int* __restrict__ idx,
        int* __restrict__ cp, int* __restrict__ srt){
    int pt = blockIdx.x*256 + threadIdx.x;
    int b14 = (pt >> 15) << 14;
    #pragma unroll
    for (int pl = 0; pl < 3; pl++){
        int pos = atomicAdd(&cp[pl*32768 + b14 + idx[pl*TT + pt]], 1);
        srt[pl*TT + pos] = pt;
    }
}

// ---- per-cell max -> mxp[pl][b*R2+cell][128] (f16), packed-f16 max ----
__global__ __launch_bounds__(256) void k_pool3(const unsigned short* __restrict__ xb,
        const int* __restrict__ srt, const int* __restrict__ cs,
        unsigned short* __restrict__ mxp){
    int pl = blockIdx.y;
    const int* srtp = srt + (size_t)pl*TT;
    const int* csp  = cs  + (size_t)pl*32769;
    int lane = threadIdx.x & 63, w = threadIdx.x >> 6;
    int g = lane >> 4, l16 = lane & 15;
    int cbase = (blockIdx.x*4 + w)*4;
    for (int c = cbase; c < cbase + 4; c++){
        int s = csp[c], e = csp[c+1];
        if (s == e) continue;
        f16x8 m;
        #pragma unroll
        for (int j = 0; j < 8; j++) m[j] = (_Float16)(-65504.f);
        for (int i = s + g; i < e; i += 4){
            int pt = srtp[i];
            f16x8 v = *(const f16x8*)(xb + (size_t)pt*128 + l16*8);
            #pragma unroll
            for (int j = 0; j < 8; j++)
                m[j] = (v[j] > m[j]) ? v[j] : m[j];
        }
        #pragma unroll
        for (int sh = 16; sh <= 32; sh += 16){
            u32x4 um = __builtin_bit_cast(u32x4, m);
            u32x4 o;
            #pragma unroll
            for (int q = 0; q < 4; q++) o[q] = __shfl_xor(um[q], sh, 64);
            f16x8 vm = __builtin_bit_cast(f16x8, o);
            #pragma unroll
            for (int j = 0; j < 8; j++)
                m[j] = (vm[j] > m[j]) ? vm[j] : m[j];
        }
        if (g == 0)
            ((u32x4*)(mxp + ((size_t)pl*32768 + c)*128))[l16] =
                __builtin_bit_cast(u32x4, m);
    }
}

// ============================================================
// fused ResnetBlockFC, M=16/wave, NW waves/block, full-tile lt,
// counted-vmcnt gather overlap (MODE 1/2).
// MODE: 0=head(fc_pos), 1=mid, 2=tail(+fc_c)
// ============================================================
template<int MODE, int NW>
__device__ __forceinline__ void resnet_body(
        const unsigned short* __restrict__ xin,
        unsigned short* __restrict__ xout,
        const unsigned short* __restrict__ wp,
        const float* __restrict__ b0, const float* __restrict__ b1,
        const int* __restrict__ idx, const unsigned short* __restrict__ mxp,
        const float* __restrict__ pin, const float* __restrict__ fW,
        const float* __restrict__ fb,
        const unsigned short* __restrict__ wc, const float* __restrict__ bc,
        unsigned short* lw, unsigned short* lt){
    int tid = threadIdx.x, w = tid >> 6, lane = tid & 63;
    int quad = lane >> 4, l15 = lane & 15;
    int m0 = blockIdx.x*(NW*16) + w*16;
    unsigned short* ltw = lt + w*LTW;

    auto stage = [&](const unsigned short* src){
        #pragma unroll
        for (int i = 0; i < 32/NW; i++){
            int chunk = i*NW + w;
            __builtin_amdgcn_global_load_lds(
                (const __attribute__((address_space(1))) unsigned*)(src + chunk*512 + lane*8),
                (__attribute__((address_space(3))) unsigned*)(lw + chunk*512),
                16, 0, 0);
        }
    };
    auto gemm = [&](const f16x8* a, f32x4 (&ac)[8]){
        #pragma unroll
        for (int ks = 0; ks < 4; ks++){
            #pragma unroll
            for (int t = 0; t < 8; t++){
                f16x8 b = *(const f16x8*)&lw[((ks*8 + t)*64 + lane)*8];
                ac[t] = MFMA16(a[ks], b, ac[t], 0, 0, 0);
            }
        }
    };

    stage(wp);          // W0a in flight
    SB0();              // pin: stage is oldest in the vmcnt queue

    // ---- A fragments ----
    u32x4 xf[4]; f16x8 pf[4];
    u32x4 g0[4], g1[4], g2[4];      // MODE 1/2: raw gathers, consumed after phase 0
    if (MODE == 0){
        int row = m0 + l15;
        float p0 = pin[row*3+0], p1 = pin[row*3+1], p2 = pin[row*3+2];
        #pragma unroll
        for (int ks = 0; ks < 4; ks++){
            int c0 = ks*32 + quad*8;
            unsigned short hx[8], hp[8];
            #pragma unroll
            for (int h = 0; h < 2; h++){
                f32x4 w0 = *(const f32x4*)(fW + c0 + h*4);
                f32x4 w1 = *(const f32x4*)(fW + 256 + c0 + h*4);
                f32x4 w2 = *(const f32x4*)(fW + 512 + c0 + h*4);
                f32x4 bb = *(const f32x4*)(fb + c0 + h*4);
                f32x4 v0 = *(const f32x4*)(fW + 128 + c0 + h*4);
                f32x4 v1 = *(const f32x4*)(fW + 384 + c0 + h*4);
                f32x4 v2 = *(const f32x4*)(fW + 640 + c0 + h*4);
                f32x4 bp = *(const f32x4*)(fb + 128 + c0 + h*4);
                #pragma unroll
                for (int j = 0; j < 4; j++){
                    hx[h*4+j] = f2h(bb[j] + p0*w0[j] + p1*w1[j] + p2*w2[j]);
                    hp[h*4+j] = f2h(bp[j] + p0*v0[j] + p1*v1[j] + p2*v2[j]);
                }
            }
            unsigned short* dx = (unsigned short*)&xf[ks];
            unsigned short* dp = (unsigned short*)&pf[ks];
            #pragma unroll
            for (int j = 0; j < 8; j++){ dx[j] = hx[j]; dp[j] = hp[j]; }
        }
    } else {
        int row = m0 + l15;
        size_t rb = (size_t)row*128;
        #pragma unroll
        for (int ks = 0; ks < 4; ks++)
            xf[ks] = *(const u32x4*)(xin + rb + ks*32 + quad*8);
        int b14 = (row >> 15) << 14;
        const unsigned short* q0 = mxp + ((size_t)(0*32768 + b14 + idx[row]))*128;
        const unsigned short* q1 = mxp + ((size_t)(1*32768 + b14 + idx[TT + row]))*128;
        const unsigned short* q2 = mxp + ((size_t)(2*32768 + b14 + idx[2*TT + row]))*128;
        #pragma unroll
        for (int ks = 0; ks < 4; ks++){
            int col = ks*32 + quad*8;
            g0[ks] = *(const u32x4*)(q0 + col);
            g1[ks] = *(const u32x4*)(q1 + col);
            g2[ks] = *(const u32x4*)(q2 + col);
        }
    }

    f32x4 acc[8];
    #pragma unroll
    for (int t = 0; t < 8; t++){ f32x4 z = {0.f,0.f,0.f,0.f}; acc[t] = z; }

    if (MODE == 0){
        VMCNT0();
    } else {
        // stage(4) is oldest; >=16 younger loads (xin 4 + gathers 12 + idx 3)
        // outstanding -> vmcnt(16) drains the stage, keeps gathers in flight.
        SB0();
        asm volatile("s_waitcnt vmcnt(16)" ::: "memory");
        SB0();
    }
    __syncthreads();                            // W0a staged

    // ---- phase 0: relu(xf) @ W0a (gathers still in flight for MODE 1/2) ----
    {
        f16x8 a[4];
        #pragma unroll
        for (int ks = 0; ks < 4; ks++){
            u32x4 u = xf[ks];
            u.x = relu2(u.x); u.y = relu2(u.y); u.z = relu2(u.z); u.w = relu2(u.w);
            a[ks] = __builtin_bit_cast(f16x8, u);
        }
        gemm(a, acc);
    }
    if (MODE != 0){
        // pf adds: compiler inserts the wait for the gather loads here
        #pragma unroll
        for (int ks = 0; ks < 4; ks++){
            f16x8 a = __builtin_bit_cast(f16x8, g0[ks]);
            f16x8 b = __builtin_bit_cast(f16x8, g1[ks]);
            f16x8 c = __builtin_bit_cast(f16x8, g2[ks]);
            pf[ks] = a + b + c;
        }
    }
    __syncthreads();
    stage(wp + 16384);
    VMCNT0(); __syncthreads();                  // W0b staged

    // ---- phase 1: relu(pf) @ W0b ----
    {
        f16x8 a[4];
        #pragma unroll
        for (int ks = 0; ks < 4; ks++){
            u32x4 u = __builtin_bit_cast(u32x4, pf[ks]);
            u.x = relu2(u.x); u.y = relu2(u.y); u.z = relu2(u.z); u.w = relu2(u.w);
            a[ks] = __builtin_bit_cast(f16x8, u);
        }
        gemm(a, acc);
    }
    __syncthreads();
    stage(wp + 32768);
    VMCNT0(); __syncthreads();                  // W1 staged

    // ---- phase 2: full-tile relu(net+b0) -> lt (releases acc), GEMM2 @ W1 ----
    {
        float b0v[8];
        #pragma unroll
        for (int t = 0; t < 8; t++) b0v[t] = b0[t*16 + l15];
        #pragma unroll
        for (int t = 0; t < 8; t++)
            #pragma unroll
            for (int r = 0; r < 4; r++){
                float v = fmaxf(acc[t][r] + b0v[t], 0.f);
                ltw[(quad*4 + r)*LTS + t*16 + l15] = f2h(v);
            }
    }
    LGKM0();
    f32x4 acc2[8];
    {
        #pragma unroll
        for (int t = 0; t < 8; t++){
            float bv = b1[t*16 + l15];
            f32x4 iv = {bv, bv, bv, bv};
            acc2[t] = iv;
        }
    }
    #pragma unroll
    for (int ks = 0; ks < 4; ks++){
        f16x8 a0 = *(const f16x8*)&ltw[l15*LTS + ks*32 + quad*8];
        #pragma unroll
        for (int t = 0; t < 8; t++){
            f16x8 b = *(const f16x8*)&lw[((ks*8 + t)*64 + lane)*8];
            acc2[t] = MFMA16(a0, b, acc2[t], 0, 0, 0);
        }
    }
    __syncthreads();
    stage(wp + 49152);
    VMCNT0(); __syncthreads();                  // Wsa staged

    // ---- phase 3: xf @ Wsa ----
    {
        f16x8 a[4];
        #pragma unroll
        for (int ks = 0; ks < 4; ks++)
            a[ks] = __builtin_bit_cast(f16x8, xf[ks]);
        gemm(a, acc2);
    }
    __syncthreads();
    stage(wp + 65536);
    VMCNT0(); __syncthreads();                  // Wsb staged

    // ---- phase 4: pf @ Wsb ----
    gemm(pf, acc2);

    if (MODE != 2){
        #pragma unroll
        for (int t = 0; t < 8; t++)
            #pragma unroll
            for (int r = 0; r < 4; r++){
                int row = m0 + quad*4 + r;
                xout[(size_t)row*128 + t*16 + l15] = f2h(acc2[t][r]);
            }
        return;
    }
    __syncthreads();
    stage(wc);
    VMCNT0(); __syncthreads();                  // Wc staged

    // ---- phase 5: full-tile net -> lt (no relu), GEMMc @ Wc ----
    #pragma unroll
    for (int t = 0; t < 8; t++)
        #pragma unroll
        for (int r = 0; r < 4; r++)
            ltw[(quad*4 + r)*LTS + t*16 + l15] = f2h(acc2[t][r]);
    LGKM0();
    f32x4 acc3[8];
    #pragma unroll
    for (int t = 0; t < 8; t++){
        float bv = bc[t*16 + l15];
        f32x4 iv = {bv, bv, bv, bv};
        acc3[t] = iv;
    }
    #pragma unroll
    for (int ks = 0; ks < 4; ks++){
        f16x8 a0 = *(const f16x8*)&ltw[l15*LTS + ks*32 + quad*8];
        #pragma unroll
        for (int t = 0; t < 8; t++){
            f16x8 b = *(const f16x8*)&lw[((ks*8 + t)*64 + lane)*8];
            acc3[t] = MFMA16(a0, b, acc3[t], 0, 0, 0);
        }
    }
    #pragma unroll
    for (int t = 0; t < 8; t++)
        #pragma unroll
        for (int r = 0; r < 4; r++){
            int row = m0 + quad*4 + r;
            xout[(size_t)row*128 + t*16 + l15] = f2h(acc3[t][r]);
        }
}

__global__ __launch_bounds__(256, 2) void k_resnet_head(
        unsigned short* __restrict__ xout, const unsigned short* __restrict__ wp,
        const float* __restrict__ b0, const float* __restrict__ b1,
        const float* __restrict__ pin, const float* __restrict__ fW,
        const float* __restrict__ fb){
    __shared__ __align__(16) unsigned short lw[16384];
    __shared__ __align__(16) unsigned short lt[8704];
    resnet_body<0,4>(nullptr, xout, wp, b0, b1, nullptr, nullptr,
                   pin, fW, fb, nullptr, nullptr, lw, lt);
}
__global__ __launch_bounds__(512, 2) void k_resnet_mid(
        const unsigned short* __restrict__ xin, unsigned short* __restrict__ xout,
        const unsigned short* __restrict__ wp,
        const float* __restrict__ b0, const float* __restrict__ b1,
        const int* __restrict__ idx, const unsigned short* __restrict__ mxp){
    __shared__ __align__(16) unsigned short lw[16384];
    __shared__ __align__(16) unsigned short lt[17408];
    resnet_body<1,8>(xin, xout, wp, b0, b1, idx, mxp,
                   nullptr, nullptr, nullptr, nullptr, nullptr, lw, lt);
}
__global__ __launch_bounds__(512, 2) void k_resnet_tail(
        const unsigned short* __restrict__ xin, unsigned short* __restrict__ xout,
        const unsigned short* __restrict__ wp,
        const float* __restrict__ b0, const float* __restrict__ b1,
        const int* __restrict__ idx, const unsigned short* __restrict__ mxp,
        const unsigned short* __restrict__ wc, const float* __restrict__ bc){
    __shared__ __align__(16) unsigned short lw[16384];
    __shared__ __align__(16) unsigned short lt[17408];
    resnet_body<2,8>(xin, xout, wp, b0, b1, idx, mxp,
                   nullptr, nullptr, nullptr, wc, bc, lw, lt);
}

// ---- scatter-mean + transpose, all planes in one launch ----
__global__ __launch_bounds__(256) void k_psum3(const unsigned short* __restrict__ cb,
        const int* __restrict__ srt, const int* __restrict__ cs,
        float* __restrict__ out){
    __shared__ float ls[32*129];
    int pl = blockIdx.y;
    const int* srtp = srt + (size_t)pl*TT;
    const int* csp  = cs  + (size_t)pl*32769;
    int tid = threadIdx.x;
    int lane = tid & 63, w = tid >> 6;
    int g = lane >> 4, l16 = lane & 15;
    int c0 = blockIdx.x * 32;
    for (int cc = w*8; cc < w*8 + 8; cc++){
        int c = c0 + cc;
        int s = csp[c], e = csp[c+1];
        float fs[8];
        #pragma unroll
        for (int j = 0; j < 8; j++) fs[j] = 0.f;
        for (int i = s + g; i < e; i += 4){
            int pt = srtp[i];
            u32x4 v = *(const u32x4*)(cb + (size_t)pt*128 + l16*8);
            #pragma unroll
            for (int q = 0; q < 4; q++){
                unsigned u = v[q];
                fs[2*q]   += h2f((unsigned short)(u & 0xFFFF));
                fs[2*q+1] += h2f((unsigned short)(u >> 16));
            }
        }
        #pragma unroll
        for (int j = 0; j < 8; j++){
            fs[j] += __shfl_xor(fs[j], 16, 64);
            fs[j] += __shfl_xor(fs[j], 32, 64);
        }
        float rc = (e > s) ? 1.f/(float)(e - s) : 0.f;
        if (g == 0){
            #pragma unroll
            for (int j = 0; j < 8; j++) ls[cc*129 + l16*8 + j] = fs[j]*rc;
        }
    }
    __syncthreads();
    int pb = pl*2 + (c0 >> 14);
    float* o = out + (size_t)pb*128*R2 + (c0 & 16383);
    #pragma unroll
    for (int k = 0; k < 16; k++){
        int lin = k*256 + tid;
        int f = lin >> 5, cc = lin & 31;
        o[(size_t)f*R2 + cc] = ls[cc*129 + f];
    }
}

extern "C" void kernel_launch(void* const* d_in, const int* in_sizes, int n_in,
                              void* d_out, int out_size, void* d_ws, size_t ws_size,
                              hipStream_t stream) {
    const float* p        = (const float*)d_in[0];
    const float* fc_pos_W = (const float*)d_in[1];
    const float* fc_pos_b = (const float*)d_in[2];
    const float* bW0      = (const float*)d_in[3];
    const float* bb0      = (const float*)d_in[4];
    const float* bW1      = (const float*)d_in[5];
    const float* bb1      = (const float*)d_in[6];
    const float* bWs      = (const float*)d_in[7];
    const float* fc_c_W   = (const float*)d_in[8];
    const float* fc_c_b   = (const float*)d_in[9];
    float* out = (float*)d_out;

    char* ws = (char*)d_ws;
    int*            idx   = (int*)ws;                          //    786,432 B
    unsigned short* net0  = (unsigned short*)(ws + 786432);    // 16,777,216 B
    unsigned short* net1  = (unsigned short*)(ws + 17563648);  // 16,777,216 B
    unsigned short* cbuf  = (unsigned short*)(ws + 34340864);  // 16,777,216 B
    int*            srt   = (int*)(ws + 51118080);             //    786,432 B
    int*            cs    = (int*)(ws + 51904512);             //    393,232 B
    int*            cp    = (int*)(ws + 52297744);             //    393,216 B
    unsigned short* wpack = (unsigned short*)(ws + 52690960);  //    851,968 B
    unsigned short* mxp   = (unsigned short*)(ws + 53542928);  // 25,165,824 B

    k_repack <<<104, 256, 0, stream>>>(bW0, bW1, bWs, fc_c_W, wpack, cp);
    k_idxhist<<<256, 256, 0, stream>>>(p, idx, cp);
    k_scan   <<<3, 1024, 0, stream>>>(cp, cs, cp);
    k_scatter<<<256, 256, 0, stream>>>(idx, cp, srt);

    // resnet 0: fc_pos fused -> net0
    k_resnet_head<<<1024, 256, 0, stream>>>(net0, wpack, bb0, bb1,
            p, fc_pos_W, fc_pos_b);

    // resnet 1..3: pool -> mxp, gather-resnet, ping-pong
    k_pool3<<<dim3(2048, 3), 256, 0, stream>>>(net0, srt, cs, mxp);
    k_resnet_mid<<<512, 512, 0, stream>>>(net0, net1, wpack + 81920,
            bb0 + 128, bb1 + 128, idx, mxp);
    k_pool3<<<dim3(2048, 3), 256, 0, stream>>>(net1, srt, cs, mxp);
    k_resnet_mid<<<512, 512, 0, stream>>>(net1, net0, wpack + 163840,
            bb0 + 256, bb1 + 256, idx, mxp);
    k_pool3<<<dim3(2048, 3), 256, 0, stream>>>(net0, srt, cs, mxp);
    k_resnet_mid<<<512, 512, 0, stream>>>(net0, net1, wpack + 245760,
            bb0 + 384, bb1 + 384, idx, mxp);
    // resnet 4: fused fc_c -> cbuf
    k_pool3<<<dim3(2048, 3), 256, 0, stream>>>(net1, srt, cs, mxp);
    k_resnet_tail<<<512, 512, 0, stream>>>(net1, cbuf, wpack + 327680,
            bb0 + 512, bb1 + 512, idx, mxp, wpack + 409600, fc_c_b);

    k_psum3<<<dim3(1024, 3), 256, 0, stream>>>(cbuf, srt, cs, out);
}